// Round 4
// baseline (1003.659 us; speedup 1.0000x reference)
//
#include <hip/hip_runtime.h>
#include <cstdint>
#include <cstddef>

// Problem constants
#define LSEQ 2048
#define NB   2      // batch
#define CCH  1024   // channels
#define NHD  16     // heads
#define HDD  64     // head dim
#define FFC  4096   // conv hidden
#define KW   9      // conv kernel width
#define MROWS 4096  // L*B

typedef __bf16 bf16x8 __attribute__((ext_vector_type(8)));
typedef float  floatx4 __attribute__((ext_vector_type(4)));
typedef unsigned short ushort4v __attribute__((ext_vector_type(4)));

__device__ inline unsigned short f2bf(float f) {
  union { float f; unsigned u; } v; v.f = f;
  unsigned r = v.u + 0x7FFFu + ((v.u >> 16) & 1u);
  return (unsigned short)(r >> 16);
}

// async global->LDS, 16B per lane. Dest must be wave-uniform base + lane*16.
__device__ inline void gload_lds16(const unsigned short* g, unsigned short* l) {
  __builtin_amdgcn_global_load_lds(
      (__attribute__((address_space(1))) unsigned int*)(g),
      (__attribute__((address_space(3))) unsigned int*)(l), 16, 0, 0);
}

// ---------------- element-wise converts ----------------
__global__ void f2bf4_kernel(const float* __restrict__ in, unsigned short* __restrict__ out, int n4) {
  int idx = blockIdx.x * 256 + threadIdx.x;
  if (idx >= n4) return;
  const floatx4 v = ((const floatx4*)in)[idx];
  unsigned long long pk = (unsigned long long)f2bf(v[0]) |
                          ((unsigned long long)f2bf(v[1]) << 16) |
                          ((unsigned long long)f2bf(v[2]) << 32) |
                          ((unsigned long long)f2bf(v[3]) << 48);
  ((unsigned long long*)out)[idx] = pk;
}

// conv1_w (FF, C, K) fp32 -> w1p[f*9216 + k*1024 + c] bf16.
__global__ __launch_bounds__(256) void repack_w1_kernel(const float* __restrict__ in,
                                                        unsigned short* __restrict__ out) {
  __shared__ unsigned short t[9216];
  const int f = blockIdx.x, tid = threadIdx.x;
  const float* src = in + (size_t)f * 9216;
#pragma unroll
  for (int rnd = 0; rnd < 9; ++rnd) {
    const int p = (rnd * 256 + tid) * 4;
    const floatx4 v = *(const floatx4*)(src + p);
#pragma unroll
    for (int e = 0; e < 4; ++e) {
      const int idx = p + e;
      const int c = idx / 9, k = idx - c * 9;
      t[k * 1024 + c] = f2bf(v[e]);
    }
  }
  __syncthreads();
  unsigned short* dst = out + (size_t)f * 9216;
#pragma unroll
  for (int rnd = 0; rnd < 9; ++rnd) {
    const int j = (rnd * 256 + tid) * 4;
    *(ushort4v*)(dst + j) = *(const ushort4v*)&t[j];
  }
}

__global__ void zero_u16(unsigned short* p, int n) {
  int idx = blockIdx.x * 256 + threadIdx.x;
  if (idx < n) p[idx] = 0;
}

// ---------------- GEMM: C = A(MxK) * B(NxK)^T + bias ----------------
// 128xBN tile, BK=64 (32KB LDS single-buffer: halves barrier pairs vs BK=32;
// BK=128 would need 64KB and regress occupancy, m132), 4 waves, 16x16x32 MFMA.
// LDS rows are 64 elems / 8 chunks; XOR swizzle chunk' = chunk ^ (row&7)
// (geometry validated by attn_kernel: 0 conflicts).
// XCD swizzle: grid is 1-D, flat&7 = XCD (dispatch round-robin); each XCD owns
// NYP consecutive B panels -> B panel fetched by one XCD's L2 only.
// EPI 0: qkv scatter.  EPI 1: fp32 out.  EPI 2: relu->bf16 out.
// KDEC (conv1): segment-outer so inner K-loop is uniform pointer bumps.
template <int EPI, bool KDEC, int BN>
__global__ __launch_bounds__(256) void gemm_bt(
    const unsigned short* __restrict__ A, const unsigned short* __restrict__ Bm,
    const float* __restrict__ bias, int N, int K, int NYP,
    float* __restrict__ outF, unsigned short* __restrict__ outB,
    unsigned short* __restrict__ qb, unsigned short* __restrict__ kb,
    unsigned short* __restrict__ vtb) {
  constexpr int JN = BN / 32;   // j-fragments per wave
  constexpr int BR = BN / 32;   // B staging rounds (BN*64/8/256)
  __shared__ alignas(16) unsigned short lA[128 * 64];
  __shared__ alignas(16) unsigned short lB[BN * 64];
  const int tid = threadIdx.x;
  const int flat = blockIdx.x;
  const int xcd = flat & 7;
  const int idx = flat >> 3;
  const int m0 = (idx & 31) * 128;
  const int n0 = (xcd * NYP + (idx >> 5)) * BN;
  const int wave = tid >> 6, lane = tid & 63;
  const int wm = (wave >> 1) * 64, wn = (wave & 1) * (BN / 2);
  const int l16 = lane & 15, quad = lane >> 4;
  const int e3 = l16 & 7;
  const int fsw0 = ((quad ^ e3) << 3);        // k-sub 0 chunk offset
  const int fsw1 = (((quad | 4) ^ e3) << 3);  // k-sub 1 chunk offset

  // loop-invariant per-thread staging offsets (4 A rounds, BR B rounds)
  size_t aoff[4], boff[BR];
#pragma unroll
  for (int i = 0; i < 4; ++i) {
    const int cf = i * 256 + tid;
    const int row = cf >> 3, cs = cf & 7;
    const int col = ((cs ^ (row & 7)) << 3);
    aoff[i] = (KDEC ? (size_t)row * 1024 : (size_t)(m0 + row) * K) + col;
  }
#pragma unroll
  for (int i = 0; i < BR; ++i) {
    const int cf = i * 256 + tid;
    const int row = cf >> 3, cs = cf & 7;
    const int col = ((cs ^ (row & 7)) << 3);
    boff[i] = (size_t)(n0 + row) * K + col;
  }

  floatx4 acc[4][JN];
#pragma unroll
  for (int i = 0; i < 4; ++i)
#pragma unroll
    for (int j = 0; j < JN; ++j) acc[i][j] = (floatx4){0.f, 0.f, 0.f, 0.f};

  auto kstep = [&](const unsigned short* Ab, const unsigned short* Bb) {
    __syncthreads();
#pragma unroll
    for (int i = 0; i < 4; ++i)
      gload_lds16(Ab + aoff[i], &lA[(i * 256 + tid) * 8]);
#pragma unroll
    for (int i = 0; i < BR; ++i)
      gload_lds16(Bb + boff[i], &lB[(i * 256 + tid) * 8]);
    __syncthreads();
    bf16x8 af[4], bf[JN];
    // k-sub 0
#pragma unroll
    for (int i = 0; i < 4; ++i)
      af[i] = *(const bf16x8*)&lA[(wm + i * 16 + l16) * 64 + fsw0];
#pragma unroll
    for (int j = 0; j < JN; ++j)
      bf[j] = *(const bf16x8*)&lB[(wn + j * 16 + l16) * 64 + fsw0];
#pragma unroll
    for (int i = 0; i < 4; ++i)
#pragma unroll
      for (int j = 0; j < JN; ++j)
        acc[i][j] = __builtin_amdgcn_mfma_f32_16x16x32_bf16(af[i], bf[j], acc[i][j], 0, 0, 0);
    // k-sub 1
#pragma unroll
    for (int i = 0; i < 4; ++i)
      af[i] = *(const bf16x8*)&lA[(wm + i * 16 + l16) * 64 + fsw1];
#pragma unroll
    for (int j = 0; j < JN; ++j)
      bf[j] = *(const bf16x8*)&lB[(wn + j * 16 + l16) * 64 + fsw1];
#pragma unroll
    for (int i = 0; i < 4; ++i)
#pragma unroll
      for (int j = 0; j < JN; ++j)
        acc[i][j] = __builtin_amdgcn_mfma_f32_16x16x32_bf16(af[i], bf[j], acc[i][j], 0, 0, 0);
  };

  if (KDEC) {
    for (int seg = 0; seg < KW; ++seg) {
      const unsigned short* Ab = A + (size_t)(m0 + seg * NB) * 1024;
      const unsigned short* Bb = Bm + seg * 1024;
      for (int kk = 0; kk < 1024; kk += 64) kstep(Ab + kk, Bb + kk);
    }
  } else {
    for (int k0 = 0; k0 < K; k0 += 64) kstep(A + k0, Bm + k0);
  }

  // epilogue: C row = m0+wm+i*16+quad*4+r, col = n0+wn+j*16+l16
#pragma unroll
  for (int i = 0; i < 4; ++i) {
#pragma unroll
    for (int j = 0; j < JN; ++j) {
      const int colg = n0 + wn + j * 16 + l16;
      const int rbase = m0 + wm + i * 16 + quad * 4;
      float vv[4];
#pragma unroll
      for (int r = 0; r < 4; ++r) vv[r] = acc[i][j][r] + bias[colg];
      if (EPI == 1) {
#pragma unroll
        for (int r = 0; r < 4; ++r) outF[(size_t)(rbase + r) * N + colg] = vv[r];
      } else if (EPI == 2) {
#pragma unroll
        for (int r = 0; r < 4; ++r)
          outB[(size_t)(rbase + r) * N + colg] = f2bf(fmaxf(vv[r], 0.f));
      } else {
        if (colg < 1024) {
          const int h = colg >> 6, d = colg & 63;
#pragma unroll
          for (int r = 0; r < 4; ++r) {
            const int row = rbase + r, l = row >> 1, b = row & 1;
            qb[(((size_t)(b * NHD + h)) * LSEQ + l) * HDD + d] = f2bf(vv[r] * 0.125f);
          }
        } else if (colg < 2048) {
          const int c = colg - 1024, h = c >> 6, d = c & 63;
#pragma unroll
          for (int r = 0; r < 4; ++r) {
            const int row = rbase + r, l = row >> 1, b = row & 1;
            kb[(((size_t)(b * NHD + h)) * LSEQ + l) * HDD + d] = f2bf(vv[r]);
          }
        } else {
          const int c = colg - 2048, h = c >> 6, d = c & 63;
#pragma unroll
          for (int rp = 0; rp < 2; ++rp) {
            const int row = rbase + rp, l = row >> 1, b = row & 1;
            const unsigned lo = f2bf(vv[rp]), hi = f2bf(vv[rp + 2]);
            *(unsigned*)&vtb[(((size_t)(b * NHD + h)) * HDD + d) * LSEQ + l] =
                lo | (hi << 16);
          }
        }
      }
    }
  }
}

// ---------------- flash attention ----------------
__global__ __launch_bounds__(256) void attn_kernel(
    const unsigned short* __restrict__ qg, const unsigned short* __restrict__ kg,
    const unsigned short* __restrict__ vtg, unsigned short* __restrict__ ao) {
  __shared__ alignas(16) unsigned short lK[64 * 64];   // [key][d] swizzled
  __shared__ alignas(16) unsigned short lV[64 * 64];   // [d][key] swizzled
  __shared__ alignas(16) unsigned short lP[4][16 * 64];
  const int tid = threadIdx.x;
  const int wave = tid >> 6, lane = tid & 63;
  const int l16 = lane & 15, quad = lane >> 4;
  const int sw0 = ((quad ^ (l16 & 7)) << 3);
  const int sw1 = (((quad | 4) ^ (l16 & 7)) << 3);
  const int qt = blockIdx.x, h = blockIdx.y, b = blockIdx.z;
  const unsigned short* Q = qg + ((size_t)(b * NHD + h) * LSEQ) * HDD;
  const unsigned short* Kp = kg + ((size_t)(b * NHD + h) * LSEQ) * HDD;
  const unsigned short* Vt = vtg + ((size_t)(b * NHD + h) * HDD) * LSEQ;
  const int q0 = qt * 64 + wave * 16;

  const bf16x8 qa0 = *(const bf16x8*)&Q[(size_t)(q0 + l16) * HDD + quad * 8];
  const bf16x8 qa1 = *(const bf16x8*)&Q[(size_t)(q0 + l16) * HDD + 32 + quad * 8];

  float mr[4], lr[4];
  floatx4 o[4];
#pragma unroll
  for (int r = 0; r < 4; ++r) { mr[r] = -1e30f; lr[r] = 0.f; }
#pragma unroll
  for (int nb = 0; nb < 4; ++nb) o[nb] = (floatx4){0.f, 0.f, 0.f, 0.f};

  for (int kt = 0; kt < LSEQ; kt += 64) {
    __syncthreads();
#pragma unroll
    for (int i = 0; i < 2; ++i) {
      const int flat = i * 256 + tid;
      const int row = flat >> 3, cs = flat & 7;
      const int col = ((cs ^ (row & 7)) << 3);
      gload_lds16(&Kp[(size_t)(kt + row) * HDD + col], &lK[flat * 8]);
      gload_lds16(&Vt[(size_t)row * LSEQ + kt + col], &lV[flat * 8]);
    }
    __syncthreads();
    floatx4 s[4];
#pragma unroll
    for (int nb = 0; nb < 4; ++nb) {
      const bf16x8 kf0 = *(const bf16x8*)&lK[(nb * 16 + l16) * 64 + sw0];
      const bf16x8 kf1 = *(const bf16x8*)&lK[(nb * 16 + l16) * 64 + sw1];
      floatx4 t = (floatx4){0.f, 0.f, 0.f, 0.f};
      t = __builtin_amdgcn_mfma_f32_16x16x32_bf16(qa0, kf0, t, 0, 0, 0);
      t = __builtin_amdgcn_mfma_f32_16x16x32_bf16(qa1, kf1, t, 0, 0, 0);
      s[nb] = t;
    }
    float mnew[4], alpha[4];
#pragma unroll
    for (int r = 0; r < 4; ++r) {
      float mx = fmaxf(fmaxf(s[0][r], s[1][r]), fmaxf(s[2][r], s[3][r]));
      mx = fmaxf(mx, __shfl_xor(mx, 1));
      mx = fmaxf(mx, __shfl_xor(mx, 2));
      mx = fmaxf(mx, __shfl_xor(mx, 4));
      mx = fmaxf(mx, __shfl_xor(mx, 8));
      mnew[r] = fmaxf(mr[r], mx);
      alpha[r] = __expf(mr[r] - mnew[r]);
      mr[r] = mnew[r];
    }
#pragma unroll
    for (int nb = 0; nb < 4; ++nb)
#pragma unroll
      for (int r = 0; r < 4; ++r) s[nb][r] = __expf(s[nb][r] - mnew[r]);
#pragma unroll
    for (int r = 0; r < 4; ++r) {
      float sm = s[0][r] + s[1][r] + s[2][r] + s[3][r];
      sm += __shfl_xor(sm, 1);
      sm += __shfl_xor(sm, 2);
      sm += __shfl_xor(sm, 4);
      sm += __shfl_xor(sm, 8);
      lr[r] = lr[r] * alpha[r] + sm;
    }
#pragma unroll
    for (int nb = 0; nb < 4; ++nb)
#pragma unroll
      for (int r = 0; r < 4; ++r) {
        const int row = quad * 4 + r;
        const int q = nb * 2 + (l16 >> 3);
        lP[wave][row * 64 + ((q ^ (row & 7)) << 3) + (l16 & 7)] = f2bf(s[nb][r]);
        o[nb][r] *= alpha[r];
      }
    asm volatile("s_waitcnt lgkmcnt(0)" ::: "memory");
    const bf16x8 pa0 = *(const bf16x8*)&lP[wave][l16 * 64 + sw0];
    const bf16x8 pa1 = *(const bf16x8*)&lP[wave][l16 * 64 + sw1];
#pragma unroll
    for (int nb = 0; nb < 4; ++nb) {
      const bf16x8 vf0 = *(const bf16x8*)&lV[(nb * 16 + l16) * 64 + sw0];
      const bf16x8 vf1 = *(const bf16x8*)&lV[(nb * 16 + l16) * 64 + sw1];
      o[nb] = __builtin_amdgcn_mfma_f32_16x16x32_bf16(pa0, vf0, o[nb], 0, 0, 0);
      o[nb] = __builtin_amdgcn_mfma_f32_16x16x32_bf16(pa1, vf1, o[nb], 0, 0, 0);
    }
  }
#pragma unroll
  for (int nb = 0; nb < 4; ++nb)
#pragma unroll
    for (int r = 0; r < 4; ++r) {
      const float v = o[nb][r] / lr[r];
      const int lg = q0 + quad * 4 + r;
      ao[((size_t)lg * NB + b) * CCH + h * HDD + nb * 16 + l16] = f2bf(v);
    }
}

// ---------------- layernorm (+residual) ----------------
__global__ __launch_bounds__(256) void ln_kernel(
    const float* __restrict__ a, const float* __restrict__ c,
    const float* __restrict__ w, const float* __restrict__ bias,
    float* __restrict__ outF, unsigned short* __restrict__ outB) {
  const int row = blockIdx.x;
  const int tid = threadIdx.x;
  const floatx4 va = *(const floatx4*)(a + (size_t)row * 1024 + tid * 4);
  const floatx4 vc = *(const floatx4*)(c + (size_t)row * 1024 + tid * 4);
  float v0 = va[0] + vc[0], v1 = va[1] + vc[1], v2 = va[2] + vc[2], v3 = va[3] + vc[3];
  float s = v0 + v1 + v2 + v3;
  float ss = v0 * v0 + v1 * v1 + v2 * v2 + v3 * v3;
#pragma unroll
  for (int off = 1; off < 64; off <<= 1) {
    s += __shfl_xor(s, off);
    ss += __shfl_xor(ss, off);
  }
  __shared__ float red[8];
  const int wave = tid >> 6, lane = tid & 63;
  if (lane == 0) { red[wave] = s; red[4 + wave] = ss; }
  __syncthreads();
  s = red[0] + red[1] + red[2] + red[3];
  ss = red[4] + red[5] + red[6] + red[7];
  const float mu = s * (1.f / 1024.f);
  const float var = ss * (1.f / 1024.f) - mu * mu;
  const float rs = rsqrtf(var + 1e-5f);
  const floatx4 wv = *(const floatx4*)(w + tid * 4);
  const floatx4 bv = *(const floatx4*)(bias + tid * 4);
  const float o0 = (v0 - mu) * rs * wv[0] + bv[0];
  const float o1 = (v1 - mu) * rs * wv[1] + bv[1];
  const float o2 = (v2 - mu) * rs * wv[2] + bv[2];
  const float o3 = (v3 - mu) * rs * wv[3] + bv[3];
  *(floatx4*)(outF + (size_t)row * 1024 + tid * 4) = (floatx4){o0, o1, o2, o3};
  if (outB) {
    unsigned long long pk = (unsigned long long)f2bf(o0) |
                            ((unsigned long long)f2bf(o1) << 16) |
                            ((unsigned long long)f2bf(o2) << 32) |
                            ((unsigned long long)f2bf(o3) << 48);
    *(unsigned long long*)(outB + (size_t)row * 1024 + tid * 4) = pk;
  }
}

extern "C" void kernel_launch(void* const* d_in, const int* in_sizes, int n_in,
                              void* d_out, int out_size, void* d_ws, size_t ws_size,
                              hipStream_t stream) {
  const float* x = (const float*)d_in[0];
  const float* wqkv = (const float*)d_in[2];
  const float* bqkv = (const float*)d_in[3];
  const float* wout = (const float*)d_in[4];
  const float* bout = (const float*)d_in[5];
  const float* w1 = (const float*)d_in[6];
  const float* b1 = (const float*)d_in[7];
  const float* w2 = (const float*)d_in[8];
  const float* b2 = (const float*)d_in[9];
  const float* n1w = (const float*)d_in[10];
  const float* n1b = (const float*)d_in[11];
  const float* n2w = (const float*)d_in[12];
  const float* n2b = (const float*)d_in[13];
  float* out = (float*)d_out;

  char* ws = (char*)d_ws;
  size_t off = 0;
  auto alloc = [&](size_t bytes) -> char* {
    char* p = ws + off;
    off += (bytes + 255) & ~(size_t)255;
    return p;
  };
  unsigned short* xb    = (unsigned short*)alloc((size_t)MROWS * 1024 * 2);
  unsigned short* wqkvb = (unsigned short*)alloc((size_t)3072 * 1024 * 2);
  unsigned short* woutb = (unsigned short*)alloc((size_t)1024 * 1024 * 2);
  unsigned short* w1p   = (unsigned short*)alloc((size_t)FFC * 9216 * 2);
  unsigned short* w2b   = (unsigned short*)alloc((size_t)1024 * FFC * 2);
  unsigned short* qbuf  = (unsigned short*)alloc((size_t)NB * NHD * LSEQ * HDD * 2);
  unsigned short* kbuf  = (unsigned short*)alloc((size_t)NB * NHD * LSEQ * HDD * 2);
  unsigned short* vtbuf = (unsigned short*)alloc((size_t)NB * NHD * LSEQ * HDD * 2);
  unsigned short* ao    = (unsigned short*)alloc((size_t)MROWS * 1024 * 2);
  float*          yz    = (float*)alloc((size_t)MROWS * 1024 * 4);
  float*          x1f   = (float*)alloc((size_t)MROWS * 1024 * 4);
  unsigned short* x1p   = (unsigned short*)alloc((size_t)(LSEQ + 8) * NB * 1024 * 2);
  unsigned short* hbuf  = (unsigned short*)alloc((size_t)MROWS * FFC * 2);
  if (off > ws_size) return;  // workspace too small -> visible failure

  int n;
  n = MROWS * 1024 / 4; f2bf4_kernel<<<(n + 255) / 256, 256, 0, stream>>>(x, xb, n);
  n = 3072 * 1024 / 4;  f2bf4_kernel<<<(n + 255) / 256, 256, 0, stream>>>(wqkv, wqkvb, n);
  n = 1024 * 1024 / 4;  f2bf4_kernel<<<(n + 255) / 256, 256, 0, stream>>>(wout, woutb, n);
  n = 1024 * FFC / 4;   f2bf4_kernel<<<(n + 255) / 256, 256, 0, stream>>>(w2, w2b, n);
  repack_w1_kernel<<<FFC, 256, 0, stream>>>(w1, w1p);
  zero_u16<<<32, 256, 0, stream>>>(x1p, 8 * 1024);
  zero_u16<<<32, 256, 0, stream>>>(x1p + (size_t)(LSEQ + 4) * NB * 1024, 8 * 1024);

  // QKV projection (M=4096, N=3072, K=1024): 1-D grid 32x24, NYP=3
  gemm_bt<0, false, 128><<<32 * 24, 256, 0, stream>>>(
      xb, wqkvb, bqkv, 3072, 1024, 3, nullptr, nullptr, qbuf, kbuf, vtbuf);
  // flash attention -> ao (L*B, C) bf16
  attn_kernel<<<dim3(LSEQ / 64, NHD, NB), 256, 0, stream>>>(qbuf, kbuf, vtbuf, ao);
  // out projection (M=4096, N=1024, K=1024): BN=64, grid 32x16, NYP=2
  gemm_bt<1, false, 64><<<32 * 16, 256, 0, stream>>>(
      ao, woutb, bout, 1024, 1024, 2, yz, nullptr, nullptr, nullptr, nullptr);
  // LN1: x + yz -> x1f fp32, x1p bf16 (shifted +8 rows for l-padding)
  ln_kernel<<<MROWS, 256, 0, stream>>>(x, yz, n1w, n1b, x1f, x1p + 8 * 1024);
  // conv1 as GEMM (M=4096, N=4096, K=9216, segment-outer): grid 32x32, NYP=4
  gemm_bt<2, true, 128><<<32 * 32, 256, 0, stream>>>(
      x1p, w1p, b1, FFC, 9216, 4, nullptr, hbuf, nullptr, nullptr, nullptr);
  // conv2 pointwise (M=4096, N=1024, K=4096): BN=64, grid 32x16, NYP=2
  gemm_bt<1, false, 64><<<32 * 16, 256, 0, stream>>>(
      hbuf, w2b, b2, 1024, FFC, 2, yz, nullptr, nullptr, nullptr, nullptr);
  // LN2: x1f + yz -> out fp32
  ln_kernel<<<MROWS, 256, 0, stream>>>(x1f, yz, n2w, n2b, out, nullptr);
}

// Round 5
// 968.774 us; speedup vs baseline: 1.0360x; 1.0360x over previous
//
#include <hip/hip_runtime.h>
#include <cstdint>
#include <cstddef>

// Problem constants
#define LSEQ 2048
#define NB   2      // batch
#define CCH  1024   // channels
#define NHD  16     // heads
#define HDD  64     // head dim
#define FFC  4096   // conv hidden
#define KW   9      // conv kernel width
#define MROWS 4096  // L*B

typedef __bf16 bf16x8 __attribute__((ext_vector_type(8)));
typedef float  floatx4 __attribute__((ext_vector_type(4)));
typedef unsigned short ushort4v __attribute__((ext_vector_type(4)));

__device__ inline unsigned short f2bf(float f) {
  union { float f; unsigned u; } v; v.f = f;
  unsigned r = v.u + 0x7FFFu + ((v.u >> 16) & 1u);
  return (unsigned short)(r >> 16);
}

// async global->LDS, 16B per lane. Dest must be wave-uniform base + lane*16.
__device__ inline void gload_lds16(const unsigned short* g, unsigned short* l) {
  __builtin_amdgcn_global_load_lds(
      (__attribute__((address_space(1))) unsigned int*)(g),
      (__attribute__((address_space(3))) unsigned int*)(l), 16, 0, 0);
}

// ---------------- element-wise converts ----------------
__global__ void f2bf4_kernel(const float* __restrict__ in, unsigned short* __restrict__ out, int n4) {
  int idx = blockIdx.x * 256 + threadIdx.x;
  if (idx >= n4) return;
  const floatx4 v = ((const floatx4*)in)[idx];
  unsigned long long pk = (unsigned long long)f2bf(v[0]) |
                          ((unsigned long long)f2bf(v[1]) << 16) |
                          ((unsigned long long)f2bf(v[2]) << 32) |
                          ((unsigned long long)f2bf(v[3]) << 48);
  ((unsigned long long*)out)[idx] = pk;
}

// conv1_w (FF, C, K) fp32 -> w1p[f*9216 + k*1024 + c] bf16.
__global__ __launch_bounds__(256) void repack_w1_kernel(const float* __restrict__ in,
                                                        unsigned short* __restrict__ out) {
  __shared__ unsigned short t[9216];
  const int f = blockIdx.x, tid = threadIdx.x;
  const float* src = in + (size_t)f * 9216;
#pragma unroll
  for (int rnd = 0; rnd < 9; ++rnd) {
    const int p = (rnd * 256 + tid) * 4;
    const floatx4 v = *(const floatx4*)(src + p);
#pragma unroll
    for (int e = 0; e < 4; ++e) {
      const int idx = p + e;
      const int c = idx / 9, k = idx - c * 9;
      t[k * 1024 + c] = f2bf(v[e]);
    }
  }
  __syncthreads();
  unsigned short* dst = out + (size_t)f * 9216;
#pragma unroll
  for (int rnd = 0; rnd < 9; ++rnd) {
    const int j = (rnd * 256 + tid) * 4;
    *(ushort4v*)(dst + j) = *(const ushort4v*)&t[j];
  }
}

__global__ void zero_u16(unsigned short* p, int n) {
  int idx = blockIdx.x * 256 + threadIdx.x;
  if (idx < n) p[idx] = 0;
}

// V [bh][l][d] -> V^T [bh][d][l].  64x64 tile per block, LDS transpose,
// coalesced 8B on both sides (fixes the 64-cache-line scatter the QKV
// epilogue's direct V^T write had).
__global__ __launch_bounds__(256) void transpose_v_kernel(
    const unsigned short* __restrict__ vin, unsigned short* __restrict__ vout) {
  __shared__ unsigned short t[64][65];
  const int tid = threadIdx.x;
  const int l0 = blockIdx.x * 64, bh = blockIdx.y;
  const unsigned short* src = vin + ((size_t)bh * LSEQ + l0) * HDD;
  const int rr = tid >> 4, cc = (tid & 15) * 4;
#pragma unroll
  for (int rnd = 0; rnd < 4; ++rnd) {
    const int row = rnd * 16 + rr;
    const ushort4v v = *(const ushort4v*)(src + row * HDD + cc);
#pragma unroll
    for (int e = 0; e < 4; ++e) t[row][cc + e] = v[e];
  }
  __syncthreads();
  unsigned short* dst = vout + (size_t)bh * HDD * LSEQ + l0;
#pragma unroll
  for (int rnd = 0; rnd < 4; ++rnd) {
    const int drow = rnd * 16 + rr;
    ushort4v v;
#pragma unroll
    for (int e = 0; e < 4; ++e) v[e] = t[cc + e][drow];
    *(ushort4v*)(dst + (size_t)drow * LSEQ + cc) = v;
  }
}

// ---------------- GEMM: C = A(MxK) * B(NxK)^T + bias ----------------
// R3-proven config: 128xBN tile, BK=32, 4 waves, 16x16x32 bf16 MFMA,
// global_load_lds width=16, XOR swizzle chunk'=chunk^((row>>1)&3) (0 conflicts).
// Kstride = row stride of A/B; Klen = K range this block accumulates.
// blockIdx.z (split-K): A/B advance z*Klen; EPI1 writes outF (z=0) / outF2 (z=1).
// EPI 0: qkv scatter (q scaled 0.125; k AND v natural [b,h,l,d] layout).
// EPI 1: fp32 out (+bias if non-null).  EPI 2: relu->bf16 out.
// KDEC (conv1): segment-outer loop, uniform +32 pointer bumps inside.
template <int EPI, bool KDEC, int BN>
__global__ __launch_bounds__(256) void gemm_bt(
    const unsigned short* __restrict__ A, const unsigned short* __restrict__ Bm,
    const float* __restrict__ bias, int N, int Kstride, int Klen,
    float* __restrict__ outF, float* __restrict__ outF2,
    unsigned short* __restrict__ outB,
    unsigned short* __restrict__ qb, unsigned short* __restrict__ kb,
    unsigned short* __restrict__ vb) {
  constexpr int JN = BN / 32;  // j-fragments per wave
  __shared__ alignas(16) unsigned short lA[128 * 32];
  __shared__ alignas(16) unsigned short lB[BN * 32];
  const int tid = threadIdx.x;
  const int m0 = blockIdx.x * 128;
  const int n0 = blockIdx.y * BN;
  const int z = blockIdx.z;
  A += (size_t)z * Klen;
  Bm += (size_t)z * Klen;
  const int wave = tid >> 6, lane = tid & 63;
  const int wm = (wave >> 1) * 64, wn = (wave & 1) * (BN / 2);
  const int l16 = lane & 15, quad = lane >> 4;
  const int fsw = (quad ^ ((l16 >> 1) & 3)) << 3;

  // loop-invariant per-thread staging offsets
  size_t aoff[2], boff[BN / 64];
#pragma unroll
  for (int i = 0; i < 2; ++i) {
    const int cf = i * 256 + tid;
    const int row = cf >> 2, cs = cf & 3;
    const int col = ((cs ^ ((row >> 1) & 3)) << 3);
    aoff[i] = (KDEC ? (size_t)row * 1024 : (size_t)(m0 + row) * Kstride) + col;
  }
#pragma unroll
  for (int i = 0; i < BN / 64; ++i) {
    const int cf = i * 256 + tid;
    const int row = cf >> 2, cs = cf & 3;
    const int col = ((cs ^ ((row >> 1) & 3)) << 3);
    boff[i] = (size_t)(n0 + row) * Kstride + col;
  }

  floatx4 acc[4][JN];
#pragma unroll
  for (int i = 0; i < 4; ++i)
#pragma unroll
    for (int j = 0; j < JN; ++j) acc[i][j] = (floatx4){0.f, 0.f, 0.f, 0.f};

  auto kstep = [&](const unsigned short* Ab, const unsigned short* Bb) {
    __syncthreads();
#pragma unroll
    for (int i = 0; i < 2; ++i)
      gload_lds16(Ab + aoff[i], &lA[(i * 256 + tid) * 8]);
#pragma unroll
    for (int i = 0; i < BN / 64; ++i)
      gload_lds16(Bb + boff[i], &lB[(i * 256 + tid) * 8]);
    __syncthreads();
    bf16x8 af[4], bf[JN];
#pragma unroll
    for (int i = 0; i < 4; ++i)
      af[i] = *(const bf16x8*)&lA[(wm + i * 16 + l16) * 32 + fsw];
#pragma unroll
    for (int j = 0; j < JN; ++j)
      bf[j] = *(const bf16x8*)&lB[(wn + j * 16 + l16) * 32 + fsw];
#pragma unroll
    for (int i = 0; i < 4; ++i)
#pragma unroll
      for (int j = 0; j < JN; ++j)
        acc[i][j] = __builtin_amdgcn_mfma_f32_16x16x32_bf16(af[i], bf[j], acc[i][j], 0, 0, 0);
  };

  if (KDEC) {
    for (int seg = 0; seg < KW; ++seg) {
      const unsigned short* Ab = A + (size_t)(m0 + seg * NB) * 1024;
      const unsigned short* Bb = Bm + seg * 1024;
      for (int kk = 0; kk < 1024; kk += 32) kstep(Ab + kk, Bb + kk);
    }
  } else {
    for (int k0 = 0; k0 < Klen; k0 += 32) kstep(A + k0, Bm + k0);
  }

  // epilogue: C row = m0+wm+i*16+quad*4+r, col = n0+wn+j*16+l16
  float* outZ = (z == 0) ? outF : outF2;
#pragma unroll
  for (int i = 0; i < 4; ++i) {
#pragma unroll
    for (int j = 0; j < JN; ++j) {
      const int colg = n0 + wn + j * 16 + l16;
      const int rbase = m0 + wm + i * 16 + quad * 4;
      const float bv = bias ? bias[colg] : 0.f;
      float vv[4];
#pragma unroll
      for (int r = 0; r < 4; ++r) vv[r] = acc[i][j][r] + bv;
      if (EPI == 1) {
#pragma unroll
        for (int r = 0; r < 4; ++r) outZ[(size_t)(rbase + r) * N + colg] = vv[r];
      } else if (EPI == 2) {
#pragma unroll
        for (int r = 0; r < 4; ++r)
          outB[(size_t)(rbase + r) * N + colg] = f2bf(fmaxf(vv[r], 0.f));
      } else {
        const int seg = colg >> 10;  // 0:q 1:k 2:v
        const int c = colg & 1023, h = c >> 6, d = c & 63;
        unsigned short* dst = (seg == 0) ? qb : (seg == 1) ? kb : vb;
        const float scl = (seg == 0) ? 0.125f : 1.f;
#pragma unroll
        for (int r = 0; r < 4; ++r) {
          const int row = rbase + r, l = row >> 1, b = row & 1;
          dst[(((size_t)(b * NHD + h)) * LSEQ + l) * HDD + d] = f2bf(vv[r] * scl);
        }
      }
    }
  }
}

// ---------------- flash attention ----------------
__global__ __launch_bounds__(256) void attn_kernel(
    const unsigned short* __restrict__ qg, const unsigned short* __restrict__ kg,
    const unsigned short* __restrict__ vtg, unsigned short* __restrict__ ao) {
  __shared__ alignas(16) unsigned short lK[64 * 64];   // [key][d] swizzled
  __shared__ alignas(16) unsigned short lV[64 * 64];   // [d][key] swizzled
  __shared__ alignas(16) unsigned short lP[4][16 * 64];
  const int tid = threadIdx.x;
  const int wave = tid >> 6, lane = tid & 63;
  const int l16 = lane & 15, quad = lane >> 4;
  const int sw0 = ((quad ^ (l16 & 7)) << 3);
  const int sw1 = (((quad | 4) ^ (l16 & 7)) << 3);
  const int qt = blockIdx.x, h = blockIdx.y, b = blockIdx.z;
  const unsigned short* Q = qg + ((size_t)(b * NHD + h) * LSEQ) * HDD;
  const unsigned short* Kp = kg + ((size_t)(b * NHD + h) * LSEQ) * HDD;
  const unsigned short* Vt = vtg + ((size_t)(b * NHD + h) * HDD) * LSEQ;
  const int q0 = qt * 64 + wave * 16;

  const bf16x8 qa0 = *(const bf16x8*)&Q[(size_t)(q0 + l16) * HDD + quad * 8];
  const bf16x8 qa1 = *(const bf16x8*)&Q[(size_t)(q0 + l16) * HDD + 32 + quad * 8];

  float mr[4], lr[4];
  floatx4 o[4];
#pragma unroll
  for (int r = 0; r < 4; ++r) { mr[r] = -1e30f; lr[r] = 0.f; }
#pragma unroll
  for (int nb = 0; nb < 4; ++nb) o[nb] = (floatx4){0.f, 0.f, 0.f, 0.f};

  for (int kt = 0; kt < LSEQ; kt += 64) {
    __syncthreads();
#pragma unroll
    for (int i = 0; i < 2; ++i) {
      const int flat = i * 256 + tid;
      const int row = flat >> 3, cs = flat & 7;
      const int col = ((cs ^ (row & 7)) << 3);
      gload_lds16(&Kp[(size_t)(kt + row) * HDD + col], &lK[flat * 8]);
      gload_lds16(&Vt[(size_t)row * LSEQ + kt + col], &lV[flat * 8]);
    }
    __syncthreads();
    floatx4 s[4];
#pragma unroll
    for (int nb = 0; nb < 4; ++nb) {
      const bf16x8 kf0 = *(const bf16x8*)&lK[(nb * 16 + l16) * 64 + sw0];
      const bf16x8 kf1 = *(const bf16x8*)&lK[(nb * 16 + l16) * 64 + sw1];
      floatx4 t = (floatx4){0.f, 0.f, 0.f, 0.f};
      t = __builtin_amdgcn_mfma_f32_16x16x32_bf16(qa0, kf0, t, 0, 0, 0);
      t = __builtin_amdgcn_mfma_f32_16x16x32_bf16(qa1, kf1, t, 0, 0, 0);
      s[nb] = t;
    }
    float mnew[4], alpha[4];
#pragma unroll
    for (int r = 0; r < 4; ++r) {
      float mx = fmaxf(fmaxf(s[0][r], s[1][r]), fmaxf(s[2][r], s[3][r]));
      mx = fmaxf(mx, __shfl_xor(mx, 1));
      mx = fmaxf(mx, __shfl_xor(mx, 2));
      mx = fmaxf(mx, __shfl_xor(mx, 4));
      mx = fmaxf(mx, __shfl_xor(mx, 8));
      mnew[r] = fmaxf(mr[r], mx);
      alpha[r] = __expf(mr[r] - mnew[r]);
      mr[r] = mnew[r];
    }
#pragma unroll
    for (int nb = 0; nb < 4; ++nb)
#pragma unroll
      for (int r = 0; r < 4; ++r) s[nb][r] = __expf(s[nb][r] - mnew[r]);
#pragma unroll
    for (int r = 0; r < 4; ++r) {
      float sm = s[0][r] + s[1][r] + s[2][r] + s[3][r];
      sm += __shfl_xor(sm, 1);
      sm += __shfl_xor(sm, 2);
      sm += __shfl_xor(sm, 4);
      sm += __shfl_xor(sm, 8);
      lr[r] = lr[r] * alpha[r] + sm;
    }
#pragma unroll
    for (int nb = 0; nb < 4; ++nb)
#pragma unroll
      for (int r = 0; r < 4; ++r) {
        const int row = quad * 4 + r;
        const int q = nb * 2 + (l16 >> 3);
        lP[wave][row * 64 + ((q ^ (row & 7)) << 3) + (l16 & 7)] = f2bf(s[nb][r]);
        o[nb][r] *= alpha[r];
      }
    asm volatile("s_waitcnt lgkmcnt(0)" ::: "memory");
    const bf16x8 pa0 = *(const bf16x8*)&lP[wave][l16 * 64 + sw0];
    const bf16x8 pa1 = *(const bf16x8*)&lP[wave][l16 * 64 + sw1];
#pragma unroll
    for (int nb = 0; nb < 4; ++nb) {
      const bf16x8 vf0 = *(const bf16x8*)&lV[(nb * 16 + l16) * 64 + sw0];
      const bf16x8 vf1 = *(const bf16x8*)&lV[(nb * 16 + l16) * 64 + sw1];
      o[nb] = __builtin_amdgcn_mfma_f32_16x16x32_bf16(pa0, vf0, o[nb], 0, 0, 0);
      o[nb] = __builtin_amdgcn_mfma_f32_16x16x32_bf16(pa1, vf1, o[nb], 0, 0, 0);
    }
  }
#pragma unroll
  for (int nb = 0; nb < 4; ++nb)
#pragma unroll
    for (int r = 0; r < 4; ++r) {
      const float v = o[nb][r] / lr[r];
      const int lg = q0 + quad * 4 + r;
      ao[((size_t)lg * NB + b) * CCH + h * HDD + nb * 16 + l16] = f2bf(v);
    }
}

// ---------------- layernorm (+residuals) ----------------
// out = LN(a + c + c2? + cbias?[col]) * w + bias
__global__ __launch_bounds__(256) void ln_kernel(
    const float* __restrict__ a, const float* __restrict__ c,
    const float* __restrict__ c2, const float* __restrict__ cbias,
    const float* __restrict__ w, const float* __restrict__ bias,
    float* __restrict__ outF, unsigned short* __restrict__ outB) {
  const int row = blockIdx.x;
  const int tid = threadIdx.x;
  const floatx4 va = *(const floatx4*)(a + (size_t)row * 1024 + tid * 4);
  const floatx4 vc = *(const floatx4*)(c + (size_t)row * 1024 + tid * 4);
  float v0 = va[0] + vc[0], v1 = va[1] + vc[1], v2 = va[2] + vc[2], v3 = va[3] + vc[3];
  if (c2) {
    const floatx4 v2c = *(const floatx4*)(c2 + (size_t)row * 1024 + tid * 4);
    v0 += v2c[0]; v1 += v2c[1]; v2 += v2c[2]; v3 += v2c[3];
  }
  if (cbias) {
    const floatx4 vb = *(const floatx4*)(cbias + tid * 4);
    v0 += vb[0]; v1 += vb[1]; v2 += vb[2]; v3 += vb[3];
  }
  float s = v0 + v1 + v2 + v3;
  float ss = v0 * v0 + v1 * v1 + v2 * v2 + v3 * v3;
#pragma unroll
  for (int off = 1; off < 64; off <<= 1) {
    s += __shfl_xor(s, off);
    ss += __shfl_xor(ss, off);
  }
  __shared__ float red[8];
  const int wave = tid >> 6, lane = tid & 63;
  if (lane == 0) { red[wave] = s; red[4 + wave] = ss; }
  __syncthreads();
  s = red[0] + red[1] + red[2] + red[3];
  ss = red[4] + red[5] + red[6] + red[7];
  const float mu = s * (1.f / 1024.f);
  const float var = ss * (1.f / 1024.f) - mu * mu;
  const float rs = rsqrtf(var + 1e-5f);
  const floatx4 wv = *(const floatx4*)(w + tid * 4);
  const floatx4 bv = *(const floatx4*)(bias + tid * 4);
  const float o0 = (v0 - mu) * rs * wv[0] + bv[0];
  const float o1 = (v1 - mu) * rs * wv[1] + bv[1];
  const float o2 = (v2 - mu) * rs * wv[2] + bv[2];
  const float o3 = (v3 - mu) * rs * wv[3] + bv[3];
  *(floatx4*)(outF + (size_t)row * 1024 + tid * 4) = (floatx4){o0, o1, o2, o3};
  if (outB) {
    unsigned long long pk = (unsigned long long)f2bf(o0) |
                            ((unsigned long long)f2bf(o1) << 16) |
                            ((unsigned long long)f2bf(o2) << 32) |
                            ((unsigned long long)f2bf(o3) << 48);
    *(unsigned long long*)(outB + (size_t)row * 1024 + tid * 4) = pk;
  }
}

extern "C" void kernel_launch(void* const* d_in, const int* in_sizes, int n_in,
                              void* d_out, int out_size, void* d_ws, size_t ws_size,
                              hipStream_t stream) {
  const float* x = (const float*)d_in[0];
  const float* wqkv = (const float*)d_in[2];
  const float* bqkv = (const float*)d_in[3];
  const float* wout = (const float*)d_in[4];
  const float* bout = (const float*)d_in[5];
  const float* w1 = (const float*)d_in[6];
  const float* b1 = (const float*)d_in[7];
  const float* w2 = (const float*)d_in[8];
  const float* b2 = (const float*)d_in[9];
  const float* n1w = (const float*)d_in[10];
  const float* n1b = (const float*)d_in[11];
  const float* n2w = (const float*)d_in[12];
  const float* n2b = (const float*)d_in[13];
  float* out = (float*)d_out;

  char* ws = (char*)d_ws;
  size_t off = 0;
  auto alloc = [&](size_t bytes) -> char* {
    char* p = ws + off;
    off += (bytes + 255) & ~(size_t)255;
    return p;
  };
  unsigned short* xb    = (unsigned short*)alloc((size_t)MROWS * 1024 * 2);   // 8.4 MB
  unsigned short* wqkvb = (unsigned short*)alloc((size_t)3072 * 1024 * 2);    // 6.3 MB
  unsigned short* woutb = (unsigned short*)alloc((size_t)1024 * 1024 * 2);    // 2.1 MB
  unsigned short* w1p   = (unsigned short*)alloc((size_t)FFC * 9216 * 2);
  unsigned short* w2b   = (unsigned short*)alloc((size_t)1024 * FFC * 2);
  unsigned short* qbuf  = (unsigned short*)alloc((size_t)NB * NHD * LSEQ * HDD * 2);
  unsigned short* kbuf  = (unsigned short*)alloc((size_t)NB * NHD * LSEQ * HDD * 2);
  unsigned short* vtbuf = (unsigned short*)alloc((size_t)NB * NHD * LSEQ * HDD * 2);
  unsigned short* ao    = (unsigned short*)alloc((size_t)MROWS * 1024 * 2);
  float*          yz    = (float*)alloc((size_t)MROWS * 1024 * 4);
  float*          x1f   = (float*)alloc((size_t)MROWS * 1024 * 4);
  unsigned short* x1p   = (unsigned short*)alloc((size_t)(LSEQ + 8) * NB * 1024 * 2);
  unsigned short* hbuf  = (unsigned short*)alloc((size_t)MROWS * FFC * 2);
  if (off > ws_size) return;  // workspace too small -> visible failure
  // dead-region aliases (no extra ws):
  //   yzB (16.8 MB, conv2 z=1 output) = xb..woutb span (dead after QKV GEMM)
  //   vbuf (8.4 MB, natural-layout V) = head of hbuf (hbuf written only after attention)
  float*          yzB   = (float*)xb;
  unsigned short* vbuf  = hbuf;

  int n;
  n = MROWS * 1024 / 4; f2bf4_kernel<<<(n + 255) / 256, 256, 0, stream>>>(x, xb, n);
  n = 3072 * 1024 / 4;  f2bf4_kernel<<<(n + 255) / 256, 256, 0, stream>>>(wqkv, wqkvb, n);
  n = 1024 * 1024 / 4;  f2bf4_kernel<<<(n + 255) / 256, 256, 0, stream>>>(wout, woutb, n);
  n = 1024 * FFC / 4;   f2bf4_kernel<<<(n + 255) / 256, 256, 0, stream>>>(w2, w2b, n);
  repack_w1_kernel<<<FFC, 256, 0, stream>>>(w1, w1p);
  zero_u16<<<32, 256, 0, stream>>>(x1p, 8 * 1024);
  zero_u16<<<32, 256, 0, stream>>>(x1p + (size_t)(LSEQ + 4) * NB * 1024, 8 * 1024);

  // QKV projection (M=4096, N=3072, K=1024); q/k/v all natural [b,h,l,d]
  gemm_bt<0, false, 128><<<dim3(32, 24), 256, 0, stream>>>(
      xb, wqkvb, bqkv, 3072, 1024, 1024, nullptr, nullptr, nullptr, qbuf, kbuf, vbuf);
  // V -> V^T (coalesced LDS transpose)
  transpose_v_kernel<<<dim3(LSEQ / 64, NB * NHD), 256, 0, stream>>>(vbuf, vtbuf);
  // flash attention -> ao (L*B, C) bf16
  attn_kernel<<<dim3(LSEQ / 64, NHD, NB), 256, 0, stream>>>(qbuf, kbuf, vtbuf, ao);
  // out projection (M=4096, N=1024, K=1024) -> yz fp32
  gemm_bt<1, false, 64><<<dim3(32, 16), 256, 0, stream>>>(
      ao, woutb, bout, 1024, 1024, 1024, yz, nullptr, nullptr, nullptr, nullptr, nullptr);
  // LN1: x + yz -> x1f fp32, x1p bf16 (shifted +8 rows for l-padding)
  ln_kernel<<<MROWS, 256, 0, stream>>>(x, yz, nullptr, nullptr, n1w, n1b, x1f, x1p + 8 * 1024);
  // conv1 as GEMM (M=4096, N=4096, K=9216, segment-outer) + bias + relu -> hbuf bf16
  gemm_bt<2, true, 128><<<dim3(32, 32), 256, 0, stream>>>(
      x1p, w1p, b1, FFC, 9216, 9216, nullptr, nullptr, hbuf, nullptr, nullptr, nullptr);
  // conv2 pointwise (M=4096, N=1024, K=4096) split-K x2 -> yz, yzB (raw, bias in LN2)
  gemm_bt<1, false, 64><<<dim3(32, 16, 2), 256, 0, stream>>>(
      hbuf, w2b, nullptr, 1024, FFC, 2048, yz, yzB, nullptr, nullptr, nullptr, nullptr);
  // LN2: x1f + yz + yzB + b2 -> out fp32
  ln_kernel<<<MROWS, 256, 0, stream>>>(x1f, yz, yzB, b2, n2w, n2b, out, nullptr);
}